// Round 9
// baseline (70.717 us; speedup 1.0000x reference)
//
#include <hip/hip_runtime.h>

#define LAMBDA_NOOBJ 0.5f
#define LAMBDA_COORD 5.0f

// Double-buffered free-running global_load_lds pipeline with counted vmcnt
// (never 0 in the main loop). R8 fix: LDS trimmed to exactly 80 KB/block
// (the extra 512B reduction array pushed 2 blocks over the 160 KB pool ->
// only 1 block/CU was resident). Reduction now reuses the staging buffers.
// Finalize is folded in via a float done-counter in out[0].
__global__ __launch_bounds__(256) void yolo_loss_kernel(
    const float4* __restrict__ pred4,
    const float4* __restrict__ targ4,
    const float* __restrict__ pred,
    const float* __restrict__ targ,
    float* __restrict__ out,   // out[0]=loss+done-ctr, [1]=box, [2]=obj, [3]=noobj
    int ntiles, int ncells, int nwaves) {
  // 4 waves x 2 buffers x 640 float4 (pred 320 + targ 320) = 81920 B exactly.
  __shared__ float4 smem[8][640];

  const int lane = threadIdx.x & 63;
  const int wid  = threadIdx.x >> 6;
  const int wave_gid = (blockIdx.x * blockDim.x + threadIdx.x) >> 6;

  float4* const b0 = smem[wid * 2 + 0];
  float4* const b1 = smem[wid * 2 + 1];

  float box = 0.f, obj = 0.f, noobj = 0.f;

  auto issue = [&](int tile, float4* buf) {
    const float4* pg = pred4 + (size_t)tile * 320;
    const float4* tg = targ4 + (size_t)tile * 320;
#pragma unroll
    for (int r = 0; r < 5; ++r) {
      __builtin_amdgcn_global_load_lds(
          (const __attribute__((address_space(1))) void*)(pg + r * 64 + lane),
          (__attribute__((address_space(3))) void*)(buf + r * 64), 16, 0, 0);
      __builtin_amdgcn_global_load_lds(
          (const __attribute__((address_space(1))) void*)(tg + r * 64 + lane),
          (__attribute__((address_space(3))) void*)(buf + 320 + r * 64), 16, 0, 0);
    }
  };

  // Prologue: two tiles in flight.
  if (wave_gid < ntiles) issue(wave_gid, b0);
  if (wave_gid + nwaves < ntiles) issue(wave_gid + nwaves, b1);

  int cur = 0;
  for (int t = wave_gid; t < ntiles; t += nwaves) {
    if (t + nwaves < ntiles) {
      asm volatile("s_waitcnt vmcnt(10)" ::: "memory");
    } else {
      asm volatile("s_waitcnt vmcnt(0)" ::: "memory");
    }
    __builtin_amdgcn_sched_barrier(0);

    float4* wb = cur ? b1 : b0;
    float p[20], tv[20];
#pragma unroll
    for (int j = 0; j < 5; ++j) {
      float4 a = wb[lane * 5 + j];
      float4 b = wb[320 + lane * 5 + j];
      p[j * 4 + 0] = a.x; p[j * 4 + 1] = a.y; p[j * 4 + 2] = a.z; p[j * 4 + 3] = a.w;
      tv[j * 4 + 0] = b.x; tv[j * 4 + 1] = b.y; tv[j * 4 + 2] = b.z; tv[j * 4 + 3] = b.w;
    }
    asm volatile("s_waitcnt lgkmcnt(0)" ::: "memory");
    __builtin_amdgcn_sched_barrier(0);

    const int tn = t + 2 * nwaves;
    if (tn < ntiles) issue(tn, wb);

#pragma unroll
    for (int c = 0; c < 4; ++c) {
      float c_t = tv[c * 5];
      float cd = c_t - p[c * 5];
      cd *= cd;
      float bd = 0.f;
#pragma unroll
      for (int k = 1; k < 5; ++k) {
        float d = tv[c * 5 + k] - p[c * 5 + k];
        bd += d * d;
      }
      bool is_obj = (c_t == 1.0f);
      box   += is_obj ? bd : 0.f;
      obj   += is_obj ? cd : 0.f;
      noobj += is_obj ? 0.f : cd;
    }
    cur ^= 1;
  }

  // Generic scalar tail (ncells % 256 != 0) — empty for this size.
  {
    const int tid = blockIdx.x * blockDim.x + threadIdx.x;
    const int stride = gridDim.x * blockDim.x;
    for (int c = ntiles * 256 + tid; c < ncells; c += stride) {
      const float* pc = pred + (size_t)c * 5;
      const float* tc = targ + (size_t)c * 5;
      float c_t = tc[0];
      float cd = c_t - pc[0];
      cd *= cd;
      float bd = 0.f;
#pragma unroll
      for (int k = 1; k < 5; ++k) {
        float d = tc[k] - pc[k];
        bd += d * d;
      }
      bool is_obj = (c_t == 1.0f);
      box   += is_obj ? bd : 0.f;
      obj   += is_obj ? cd : 0.f;
      noobj += is_obj ? 0.f : cd;
    }
  }

  // Wave (64-lane) reduction.
#pragma unroll
  for (int off = 32; off > 0; off >>= 1) {
    box   += __shfl_down(box, off);
    obj   += __shfl_down(obj, off);
    noobj += __shfl_down(noobj, off);
  }

  // Cross-wave reduction: reuse the staging buffer (all DMA drained, all
  // ds_reads consumed; __syncthreads orders the reuse).
  float* red = (float*)&smem[0][0];
  __syncthreads();
  if (lane == 0) {
    red[wid * 3 + 0] = box;
    red[wid * 3 + 1] = obj;
    red[wid * 3 + 2] = noobj;
  }
  __syncthreads();
  if (threadIdx.x == 0) {
    float b = red[0] + red[3] + red[6] + red[9];
    float o = red[1] + red[4] + red[7] + red[10];
    float n = red[2] + red[5] + red[8] + red[11];
    atomicAdd(&out[1], LAMBDA_COORD * b);
    atomicAdd(&out[2], o);
    atomicAdd(&out[3], LAMBDA_NOOBJ * n);
    __threadfence();
    // out[0] doubles as a done-counter (memset to 0 each call). The last
    // block to finish computes the total loss in place of a second kernel.
    float old = atomicAdd(&out[0], 1.0f);
    if (old == (float)(gridDim.x - 1)) {
      float fb = atomicAdd(&out[1], 0.0f);   // coherent device-scope reads
      float fo = atomicAdd(&out[2], 0.0f);
      float fn = atomicAdd(&out[3], 0.0f);
      out[0] = fb + fo + fn;
    }
  }
}

extern "C" void kernel_launch(void* const* d_in, const int* in_sizes, int n_in,
                              void* d_out, int out_size, void* d_ws, size_t ws_size,
                              hipStream_t stream) {
  const float* pred = (const float*)d_in[0];
  const float* targ = (const float*)d_in[1];
  float* out = (float*)d_out;

  const int ncells = in_sizes[0] / 5;    // 6,553,600
  const int ntiles = ncells / 256;       // 25,600

  // d_out is poisoned once and never re-zeroed between replays; the kernel
  // accumulates with atomics, so zero it ourselves every call.
  (void)hipMemsetAsync(d_out, 0, out_size * sizeof(float), stream);

  // 512 blocks = 2 blocks/CU (80 KB LDS each, exactly fits the 160 KB pool)
  // = 2048 free-running waves, 12.5 tiles per wave.
  const int block = 256;
  const int grid = 512;
  const int nwaves = (grid * block) / 64;
  yolo_loss_kernel<<<grid, block, 0, stream>>>(
      (const float4*)pred, (const float4*)targ, pred, targ, out,
      ntiles, ncells, nwaves);
}

// Round 10
// 58.223 us; speedup vs baseline: 1.2146x; 1.2146x over previous
//
#include <hip/hip_runtime.h>

#define LAMBDA_NOOBJ 0.5f
#define LAMBDA_COORD 5.0f

// Triple-buffered free-running global_load_lds pipeline, counted vmcnt.
// R9 lesson: 2048 concurrent waves oversubscribe the read path (3.7 TB/s)
// vs 1024 waves (4.4 TB/s). So: grid=256 (1 block/CU persistent, 1024
// waves), and add pipeline depth per wave instead (3 tiles = ~30 KB in
// flight per wave). LDS 120 KB/block -> 1 block/CU either way.
__global__ __launch_bounds__(256) void yolo_loss_kernel(
    const float4* __restrict__ pred4,
    const float4* __restrict__ targ4,
    const float* __restrict__ pred,
    const float* __restrict__ targ,
    float* __restrict__ out,   // out[0]=loss+done-ctr, [1]=box, [2]=obj, [3]=noobj
    int ntiles, int ncells, int nwaves) {
  // 4 waves x 3 buffers x 640 float4 (pred 320 + targ 320) = 122880 B.
  __shared__ float4 smem[12][640];

  const int lane = threadIdx.x & 63;
  const int wid  = threadIdx.x >> 6;
  const int wave_gid = (blockIdx.x * blockDim.x + threadIdx.x) >> 6;

  float4* ba = smem[wid * 3 + 0];
  float4* bb = smem[wid * 3 + 1];
  float4* bc = smem[wid * 3 + 2];

  float box = 0.f, obj = 0.f, noobj = 0.f;

  auto issue = [&](int tile, float4* buf) {
    const float4* pg = pred4 + (size_t)tile * 320;
    const float4* tg = targ4 + (size_t)tile * 320;
#pragma unroll
    for (int r = 0; r < 5; ++r) {
      __builtin_amdgcn_global_load_lds(
          (const __attribute__((address_space(1))) void*)(pg + r * 64 + lane),
          (__attribute__((address_space(3))) void*)(buf + r * 64), 16, 0, 0);
      __builtin_amdgcn_global_load_lds(
          (const __attribute__((address_space(1))) void*)(tg + r * 64 + lane),
          (__attribute__((address_space(3))) void*)(buf + 320 + r * 64), 16, 0, 0);
    }
  };

  // Prologue: up to three tiles in flight.
  if (wave_gid < ntiles)              issue(wave_gid,              ba);
  if (wave_gid + nwaves < ntiles)     issue(wave_gid + nwaves,     bb);
  if (wave_gid + 2 * nwaves < ntiles) issue(wave_gid + 2 * nwaves, bc);

  for (int t = wave_gid; t < ntiles; t += nwaves) {
    // Wait for the CURRENT tile only; keep up to 2 prefetched tiles
    // (20 loads) in flight across the compute phase.
    if (t + 2 * nwaves < ntiles) {
      asm volatile("s_waitcnt vmcnt(20)" ::: "memory");
    } else if (t + nwaves < ntiles) {
      asm volatile("s_waitcnt vmcnt(10)" ::: "memory");
    } else {
      asm volatile("s_waitcnt vmcnt(0)" ::: "memory");
    }
    __builtin_amdgcn_sched_barrier(0);

    float p[20], tv[20];
#pragma unroll
    for (int j = 0; j < 5; ++j) {
      float4 a = ba[lane * 5 + j];
      float4 b = ba[320 + lane * 5 + j];
      p[j * 4 + 0] = a.x; p[j * 4 + 1] = a.y; p[j * 4 + 2] = a.z; p[j * 4 + 3] = a.w;
      tv[j * 4 + 0] = b.x; tv[j * 4 + 1] = b.y; tv[j * 4 + 2] = b.z; tv[j * 4 + 3] = b.w;
    }
    asm volatile("s_waitcnt lgkmcnt(0)" ::: "memory");
    __builtin_amdgcn_sched_barrier(0);

    const int tn = t + 3 * nwaves;
    if (tn < ntiles) issue(tn, ba);   // refill just-consumed buffer

#pragma unroll
    for (int c = 0; c < 4; ++c) {
      float c_t = tv[c * 5];
      float cd = c_t - p[c * 5];
      cd *= cd;
      float bd = 0.f;
#pragma unroll
      for (int k = 1; k < 5; ++k) {
        float d = tv[c * 5 + k] - p[c * 5 + k];
        bd += d * d;
      }
      bool is_obj = (c_t == 1.0f);
      box   += is_obj ? bd : 0.f;
      obj   += is_obj ? cd : 0.f;
      noobj += is_obj ? 0.f : cd;
    }

    // Rotate buffers (pointer rotation, no runtime array indexing).
    float4* tmp = ba; ba = bb; bb = bc; bc = tmp;
  }

  // Generic scalar tail (ncells % 256 != 0) — empty for this size.
  {
    const int tid = blockIdx.x * blockDim.x + threadIdx.x;
    const int stride = gridDim.x * blockDim.x;
    for (int c = ntiles * 256 + tid; c < ncells; c += stride) {
      const float* pc = pred + (size_t)c * 5;
      const float* tc = targ + (size_t)c * 5;
      float c_t = tc[0];
      float cd = c_t - pc[0];
      cd *= cd;
      float bd = 0.f;
#pragma unroll
      for (int k = 1; k < 5; ++k) {
        float d = tc[k] - pc[k];
        bd += d * d;
      }
      bool is_obj = (c_t == 1.0f);
      box   += is_obj ? bd : 0.f;
      obj   += is_obj ? cd : 0.f;
      noobj += is_obj ? 0.f : cd;
    }
  }

  // Wave (64-lane) reduction.
#pragma unroll
  for (int off = 32; off > 0; off >>= 1) {
    box   += __shfl_down(box, off);
    obj   += __shfl_down(obj, off);
    noobj += __shfl_down(noobj, off);
  }

  // Cross-wave reduction: reuse staging LDS (all DMA drained + consumed).
  float* red = (float*)&smem[0][0];
  __syncthreads();
  if (lane == 0) {
    red[wid * 3 + 0] = box;
    red[wid * 3 + 1] = obj;
    red[wid * 3 + 2] = noobj;
  }
  __syncthreads();
  if (threadIdx.x == 0) {
    float b = red[0] + red[3] + red[6] + red[9];
    float o = red[1] + red[4] + red[7] + red[10];
    float n = red[2] + red[5] + red[8] + red[11];
    atomicAdd(&out[1], LAMBDA_COORD * b);
    atomicAdd(&out[2], o);
    atomicAdd(&out[3], LAMBDA_NOOBJ * n);
    __threadfence();
    // out[0] doubles as done-counter (memset to 0 each call); last block
    // computes the total loss, replacing a second kernel launch.
    float old = atomicAdd(&out[0], 1.0f);
    if (old == (float)(gridDim.x - 1)) {
      float fb = atomicAdd(&out[1], 0.0f);
      float fo = atomicAdd(&out[2], 0.0f);
      float fn = atomicAdd(&out[3], 0.0f);
      out[0] = fb + fo + fn;
    }
  }
}

extern "C" void kernel_launch(void* const* d_in, const int* in_sizes, int n_in,
                              void* d_out, int out_size, void* d_ws, size_t ws_size,
                              hipStream_t stream) {
  const float* pred = (const float*)d_in[0];
  const float* targ = (const float*)d_in[1];
  float* out = (float*)d_out;

  const int ncells = in_sizes[0] / 5;    // 6,553,600
  const int ntiles = ncells / 256;       // 25,600

  // d_out is poisoned once and never re-zeroed between replays; the kernel
  // accumulates with atomics, so zero it ourselves every call.
  (void)hipMemsetAsync(d_out, 0, out_size * sizeof(float), stream);

  // 256 blocks = 1 block/CU persistent (120 KB LDS), 1024 waves,
  // 25 tiles per wave exactly.
  const int block = 256;
  const int grid = 256;
  const int nwaves = (grid * block) / 64;
  yolo_loss_kernel<<<grid, block, 0, stream>>>(
      (const float4*)pred, (const float4*)targ, pred, targ, out,
      ntiles, ncells, nwaves);
}

// Round 11
// 57.340 us; speedup vs baseline: 1.2333x; 1.0154x over previous
//
#include <hip/hip_runtime.h>

#define LAMBDA_NOOBJ 0.5f
#define LAMBDA_COORD 5.0f

// R10's triple-buffered counted-vmcnt DMA pipeline with ONE change: each
// wave owns a CONTIGUOUS span of tiles (250 KB sequential per stream)
// instead of a strided walk (10 KB then a ~10 MB jump). Tests whether DRAM
// row locality of the 2048 concurrent streams is the current limiter.
__global__ __launch_bounds__(256) void yolo_loss_kernel(
    const float4* __restrict__ pred4,
    const float4* __restrict__ targ4,
    const float* __restrict__ pred,
    const float* __restrict__ targ,
    float* __restrict__ out,   // out[0]=loss+done-ctr, [1]=box, [2]=obj, [3]=noobj
    int ntiles, int ncells, int nwaves) {
  // 4 waves x 3 buffers x 640 float4 (pred 320 + targ 320) = 122880 B.
  __shared__ float4 smem[12][640];

  const int lane = threadIdx.x & 63;
  const int wid  = threadIdx.x >> 6;
  const int wave_gid = (blockIdx.x * blockDim.x + threadIdx.x) >> 6;

  float4* ba = smem[wid * 3 + 0];
  float4* bb = smem[wid * 3 + 1];
  float4* bc = smem[wid * 3 + 2];

  float box = 0.f, obj = 0.f, noobj = 0.f;

  auto issue = [&](int tile, float4* buf) {
    const float4* pg = pred4 + (size_t)tile * 320;
    const float4* tg = targ4 + (size_t)tile * 320;
#pragma unroll
    for (int r = 0; r < 5; ++r) {
      __builtin_amdgcn_global_load_lds(
          (const __attribute__((address_space(1))) void*)(pg + r * 64 + lane),
          (__attribute__((address_space(3))) void*)(buf + r * 64), 16, 0, 0);
      __builtin_amdgcn_global_load_lds(
          (const __attribute__((address_space(1))) void*)(tg + r * 64 + lane),
          (__attribute__((address_space(3))) void*)(buf + 320 + r * 64), 16, 0, 0);
    }
  };

  // Contiguous span for this wave: [t0, t1).
  const int tpw = (ntiles + nwaves - 1) / nwaves;   // 25 for this size
  const int t0 = wave_gid * tpw;
  const int t1 = (t0 + tpw < ntiles) ? (t0 + tpw) : ntiles;

  // Prologue: up to three tiles in flight.
  if (t0 + 0 < t1) issue(t0 + 0, ba);
  if (t0 + 1 < t1) issue(t0 + 1, bb);
  if (t0 + 2 < t1) issue(t0 + 2, bc);

  for (int t = t0; t < t1; ++t) {
    // Wait for the CURRENT tile only; keep up to 2 prefetched tiles
    // (20 loads) in flight across the compute phase.
    if (t + 2 < t1) {
      asm volatile("s_waitcnt vmcnt(20)" ::: "memory");
    } else if (t + 1 < t1) {
      asm volatile("s_waitcnt vmcnt(10)" ::: "memory");
    } else {
      asm volatile("s_waitcnt vmcnt(0)" ::: "memory");
    }
    __builtin_amdgcn_sched_barrier(0);

    float p[20], tv[20];
#pragma unroll
    for (int j = 0; j < 5; ++j) {
      float4 a = ba[lane * 5 + j];
      float4 b = ba[320 + lane * 5 + j];
      p[j * 4 + 0] = a.x; p[j * 4 + 1] = a.y; p[j * 4 + 2] = a.z; p[j * 4 + 3] = a.w;
      tv[j * 4 + 0] = b.x; tv[j * 4 + 1] = b.y; tv[j * 4 + 2] = b.z; tv[j * 4 + 3] = b.w;
    }
    asm volatile("s_waitcnt lgkmcnt(0)" ::: "memory");
    __builtin_amdgcn_sched_barrier(0);

    if (t + 3 < t1) issue(t + 3, ba);   // refill just-consumed buffer

#pragma unroll
    for (int c = 0; c < 4; ++c) {
      float c_t = tv[c * 5];
      float cd = c_t - p[c * 5];
      cd *= cd;
      float bd = 0.f;
#pragma unroll
      for (int k = 1; k < 5; ++k) {
        float d = tv[c * 5 + k] - p[c * 5 + k];
        bd += d * d;
      }
      bool is_obj = (c_t == 1.0f);
      box   += is_obj ? bd : 0.f;
      obj   += is_obj ? cd : 0.f;
      noobj += is_obj ? 0.f : cd;
    }

    // Rotate buffers (pointer rotation, no runtime array indexing).
    float4* tmp = ba; ba = bb; bb = bc; bc = tmp;
  }

  // Generic scalar tail (ncells % 256 != 0) — empty for this size.
  {
    const int tid = blockIdx.x * blockDim.x + threadIdx.x;
    const int stride = gridDim.x * blockDim.x;
    for (int c = ntiles * 256 + tid; c < ncells; c += stride) {
      const float* pc = pred + (size_t)c * 5;
      const float* tc = targ + (size_t)c * 5;
      float c_t = tc[0];
      float cd = c_t - pc[0];
      cd *= cd;
      float bd = 0.f;
#pragma unroll
      for (int k = 1; k < 5; ++k) {
        float d = tc[k] - pc[k];
        bd += d * d;
      }
      bool is_obj = (c_t == 1.0f);
      box   += is_obj ? bd : 0.f;
      obj   += is_obj ? cd : 0.f;
      noobj += is_obj ? 0.f : cd;
    }
  }

  // Wave (64-lane) reduction.
#pragma unroll
  for (int off = 32; off > 0; off >>= 1) {
    box   += __shfl_down(box, off);
    obj   += __shfl_down(obj, off);
    noobj += __shfl_down(noobj, off);
  }

  // Cross-wave reduction: reuse staging LDS (all DMA drained + consumed).
  float* red = (float*)&smem[0][0];
  __syncthreads();
  if (lane == 0) {
    red[wid * 3 + 0] = box;
    red[wid * 3 + 1] = obj;
    red[wid * 3 + 2] = noobj;
  }
  __syncthreads();
  if (threadIdx.x == 0) {
    float b = red[0] + red[3] + red[6] + red[9];
    float o = red[1] + red[4] + red[7] + red[10];
    float n = red[2] + red[5] + red[8] + red[11];
    atomicAdd(&out[1], LAMBDA_COORD * b);
    atomicAdd(&out[2], o);
    atomicAdd(&out[3], LAMBDA_NOOBJ * n);
    __threadfence();
    // out[0] doubles as done-counter (memset to 0 each call); last block
    // computes the total loss, replacing a second kernel launch.
    float old = atomicAdd(&out[0], 1.0f);
    if (old == (float)(gridDim.x - 1)) {
      float fb = atomicAdd(&out[1], 0.0f);
      float fo = atomicAdd(&out[2], 0.0f);
      float fn = atomicAdd(&out[3], 0.0f);
      out[0] = fb + fo + fn;
    }
  }
}

extern "C" void kernel_launch(void* const* d_in, const int* in_sizes, int n_in,
                              void* d_out, int out_size, void* d_ws, size_t ws_size,
                              hipStream_t stream) {
  const float* pred = (const float*)d_in[0];
  const float* targ = (const float*)d_in[1];
  float* out = (float*)d_out;

  const int ncells = in_sizes[0] / 5;    // 6,553,600
  const int ntiles = ncells / 256;       // 25,600

  // d_out is poisoned once and never re-zeroed between replays; the kernel
  // accumulates with atomics, so zero it ourselves every call.
  (void)hipMemsetAsync(d_out, 0, out_size * sizeof(float), stream);

  // 256 blocks = 1 block/CU persistent (120 KB LDS), 1024 waves,
  // each owning a contiguous span of 25 tiles (250 KB per stream).
  const int block = 256;
  const int grid = 256;
  const int nwaves = (grid * block) / 64;
  yolo_loss_kernel<<<grid, block, 0, stream>>>(
      (const float4*)pred, (const float4*)targ, pred, targ, out,
      ntiles, ncells, nwaves);
}